// Round 9
// baseline (160.990 us; speedup 1.0000x reference)
//
#include <hip/hip_runtime.h>
#include <math.h>

// Sizes fixed by the reference problem.
#define Bn 32
#define Sn 8192
#define Dn 256
#define Cn 512                 // 2*D
#define NBLK 1024              // ga_fused grid = exactly 4 blocks/CU x 256 CUs
#define NFIN 256               // finalize units = 32 batches x 8 slices
#define NEG_BIG (-1e30f)

// Workspace layout (float offsets). ~3.2 MiB total.
#define WS_U     0                          // [512]  u[c] = sum_d va[d]*Ua[d,c]
#define WS_QV    512                        // [32]   qv[b] = input[b] . (Wa^T va)
#define WS_PM    544                        // [NBLK] per-block running max
#define WS_PL    (WS_PM + NBLK)             // [NBLK] per-block exp-sum
#define WS_PLAN  (WS_PL + NBLK)             // [NBLK] packed (b,t0,t1) ints
#define WS_BAR   (WS_PLAN + NBLK)           // [16]   grid-barrier counter (uint)
#define WS_ALIGN (WS_BAR + 16)              // [B*S]  raw align (valid rows only)
#define WS_PACC  (WS_ALIGN + Bn * Sn)       // [NBLK*Cn] per-block weighted ctx

// ---------------------------------------------------------------------------
// Length-proportional partition of the global 16-row-tile space (see R8).
// cnt <= 65 per batch; every block gets >= 1 tile. All int32 safe.
__device__ inline void ga_partition(const int* __restrict__ lens, int k,
                                    int& b, int& t0, int& t1) {
  int TOT = 0;
#pragma unroll
  for (int i = 0; i < Bn; ++i) TOT += (lens[i] + 15) >> 4;
  int P = 0, bb = 0, offb = 0, cntb = 1, ntb = 1;
#pragma unroll
  for (int i = 0; i < Bn; ++i) {
    const int nt = (lens[i] + 15) >> 4;
    const int o0 = (P * NBLK) / TOT;
    const int o1 = ((P + nt) * NBLK) / TOT;
    if (k >= o0 && k < o1) { bb = i; offb = o0; cntb = o1 - o0; ntb = nt; }
    P += nt;
  }
  const int j = k - offb;
  b = bb;
  t0 = (j * ntb) / cntb;
  t1 = ((j + 1) * ntb) / cntb;
}

__device__ inline void ga_batch_range(const int* __restrict__ lens, int b,
                                      int& offb, int& cntb) {
  int TOT = 0;
#pragma unroll
  for (int i = 0; i < Bn; ++i) TOT += (lens[i] + 15) >> 4;
  int P = 0;
  for (int i = 0; i < b; ++i) P += (lens[i] + 15) >> 4;
  const int nt = (lens[b] + 15) >> 4;
  offb = (P * NBLK) / TOT;
  cntb = ((P + nt) * NBLK) / TOT - offb;
}

// ---------------------------------------------------------------------------
// K1: ONE dispatch does all prep, no cross-block dependencies.
//   blocks 0..7 : u[64bx..64bx+64) -- each block reduces its 4 row-quarters
//                 in LDS (direct column result, no global partials)
//   block  8    : w[d] = sum_e va[e]*Wa[e,d], then qv[b] = input[b].w
//   blocks 9..12: partition plan (one packed entry per ga_fused block);
//                 block 9 also zeroes the grid-barrier counter -- this makes
//                 K2's barrier safe against workspace poison on every replay.
__global__ __launch_bounds__(256) void ga_prep(const float* __restrict__ input,
                                               const float* __restrict__ Wa,
                                               const float* __restrict__ Ua,
                                               const float* __restrict__ va,
                                               const int* __restrict__ lens,
                                               float* __restrict__ ws) {
  const int tid = threadIdx.x, bx = blockIdx.x;
  if (bx < 8) {
    const int c = bx * 64 + (tid & 63);
    const int q = tid >> 6;                 // row quarter
    float acc = 0.f;
#pragma unroll 8
    for (int i = 0; i < 64; ++i) {
      const int d = q * 64 + i;
      acc += va[d] * Ua[(size_t)d * Cn + c];
    }
    __shared__ float sh[4][64];
    sh[q][tid & 63] = acc;
    __syncthreads();
    if (tid < 64)
      ws[WS_U + bx * 64 + tid] = sh[0][tid] + sh[1][tid] + sh[2][tid] + sh[3][tid];
  } else if (bx == 8) {
    __shared__ float wsh[Dn];
    float acc = 0.f;
#pragma unroll 8
    for (int e = 0; e < Dn; ++e)
      acc += va[e] * Wa[(size_t)e * Dn + tid];   // coalesced across tid
    wsh[tid] = acc;
    __syncthreads();
    const int b = tid >> 3, l8 = tid & 7;   // 8 threads per batch
    float p = 0.f;
#pragma unroll
    for (int j = 0; j < Dn / 8; ++j) {
      const int d = l8 + j * 8;
      p += input[b * Dn + d] * wsh[d];
    }
    p += __shfl_xor(p, 1);
    p += __shfl_xor(p, 2);
    p += __shfl_xor(p, 4);
    if (l8 == 0) ws[WS_QV + b] = p;
  } else {
    const int k = (bx - 9) * 256 + tid;     // 0..NBLK-1
    int b, t0, t1;
    ga_partition(lens, k, b, t0, t1);
    ((int*)ws)[WS_PLAN + k] = b | (t0 << 5) | (t1 << 17);  // 5+12+12 bits
    if (bx == 9 && tid == 0) ((unsigned*)ws)[WS_BAR] = 0u;
  }
}

// ---------------------------------------------------------------------------
// K2: main loop (R8 structure: 16-lane-group rows, 4 streams/wave, 8 KiB in
// flight, branch-free online softmax) + in-kernel grid barrier + finalize.
// After writing its partials each block arrives at the barrier counter; the
// first NBLK-NFIN arrivers EXIT (freeing CUs), the last NFIN arrivers each
// claim one finalize unit by arrival order (unit work is fixed -> results
// deterministic), poll the counter to NBLK, then run finalize.
__global__ __launch_bounds__(256, 4) void ga_fused(const float* __restrict__ context,
                                                   const int* __restrict__ lens,
                                                   float* __restrict__ ws,
                                                   float* __restrict__ out) {
  const int k = blockIdx.x;
  const int plan = ((const int*)ws)[WS_PLAN + k];
  const int b  = plan & 31;
  const int t0 = (plan >> 5)  & 0xFFF;
  const int t1 = (plan >> 17) & 0xFFF;
  const int tid  = threadIdx.x;
  const int wave = tid >> 6;
  const int lane = tid & 63;
  const int l16  = lane & 15;          // chunk id within row
  const int slot = lane >> 4;          // stream id within wave
  const int len = lens[b];
  const float qv = ws[WS_QV + b];

  // u fragment: fixed per lane, loaded once (32 VGPR)
  const float4* uv = (const float4*)(ws + WS_U);
  float4 u0 = uv[l16 +  0], u1 = uv[l16 + 16], u2 = uv[l16 + 32], u3 = uv[l16 + 48];
  float4 u4 = uv[l16 + 64], u5 = uv[l16 + 80], u6 = uv[l16 + 96], u7 = uv[l16 + 112];

  float m = NEG_BIG, l = 0.f;
  float4 a0 = make_float4(0.f,0.f,0.f,0.f), a1 = a0, a2 = a0, a3 = a0;
  float4 a4 = a0, a5 = a0, a6 = a0, a7 = a0;

  const float* cbase = context + (size_t)b * Sn * Cn;
  float* alout = ws + WS_ALIGN + (size_t)b * Sn;

  for (int t = t0; t < t1; ++t) {
    const int s = t * 16 + wave * 4 + slot;            // < Sn always
    const float4* p = (const float4*)(cbase + (size_t)s * Cn) + l16;
    const float4 f0 = p[0],  f1 = p[16], f2 = p[32], f3 = p[48];
    const float4 f4 = p[64], f5 = p[80], f6 = p[96], f7 = p[112];

    float dot = f0.x*u0.x + f0.y*u0.y + f0.z*u0.z + f0.w*u0.w
              + f1.x*u1.x + f1.y*u1.y + f1.z*u1.z + f1.w*u1.w
              + f2.x*u2.x + f2.y*u2.y + f2.z*u2.z + f2.w*u2.w
              + f3.x*u3.x + f3.y*u3.y + f3.z*u3.z + f3.w*u3.w
              + f4.x*u4.x + f4.y*u4.y + f4.z*u4.z + f4.w*u4.w
              + f5.x*u5.x + f5.y*u5.y + f5.z*u5.z + f5.w*u5.w
              + f6.x*u6.x + f6.y*u6.y + f6.z*u6.z + f6.w*u6.w
              + f7.x*u7.x + f7.y*u7.y + f7.z*u7.z + f7.w*u7.w;
    dot += __shfl_xor(dot, 1);
    dot += __shfl_xor(dot, 2);
    dot += __shfl_xor(dot, 4);
    dot += __shfl_xor(dot, 8);                         // full row dot in group

    const bool valid = (s < len);
    const float al = valid ? (qv + dot) : -INFINITY;
    if (l16 == 0 && valid) alout[s] = al;

    const float mn = fmaxf(m, al);                     // invalid: mn=m
    const float sc = __expf(m - mn);                   // invalid: exp(0)=1
    const float pw = __expf(al - mn);                  // invalid: exp(-inf)=0
    l = l * sc + pw;
    a0.x=a0.x*sc+pw*f0.x; a0.y=a0.y*sc+pw*f0.y; a0.z=a0.z*sc+pw*f0.z; a0.w=a0.w*sc+pw*f0.w;
    a1.x=a1.x*sc+pw*f1.x; a1.y=a1.y*sc+pw*f1.y; a1.z=a1.z*sc+pw*f1.z; a1.w=a1.w*sc+pw*f1.w;
    a2.x=a2.x*sc+pw*f2.x; a2.y=a2.y*sc+pw*f2.y; a2.z=a2.z*sc+pw*f2.z; a2.w=a2.w*sc+pw*f2.w;
    a3.x=a3.x*sc+pw*f3.x; a3.y=a3.y*sc+pw*f3.y; a3.z=a3.z*sc+pw*f3.z; a3.w=a3.w*sc+pw*f3.w;
    a4.x=a4.x*sc+pw*f4.x; a4.y=a4.y*sc+pw*f4.y; a4.z=a4.z*sc+pw*f4.z; a4.w=a4.w*sc+pw*f4.w;
    a5.x=a5.x*sc+pw*f5.x; a5.y=a5.y*sc+pw*f5.y; a5.z=a5.z*sc+pw*f5.z; a5.w=a5.w*sc+pw*f5.w;
    a6.x=a6.x*sc+pw*f6.x; a6.y=a6.y*sc+pw*f6.y; a6.z=a6.z*sc+pw*f6.z; a6.w=a6.w*sc+pw*f6.w;
    a7.x=a7.x*sc+pw*f7.x; a7.y=a7.y*sc+pw*f7.y; a7.z=a7.z*sc+pw*f7.z; a7.w=a7.w*sc+pw*f7.w;
    m = mn;
  }

  // ---- merge the wave's 4 lane-group streams ----
  float mw = fmaxf(m, __shfl_xor(m, 16));
  mw = fmaxf(mw, __shfl_xor(mw, 32));
  const float fS = __expf(m - mw);
  float lw = l * fS;
  lw += __shfl_xor(lw, 16);
  lw += __shfl_xor(lw, 32);
#define MRG(A) \
  A.x*=fS; A.y*=fS; A.z*=fS; A.w*=fS; \
  A.x+=__shfl_xor(A.x,16); A.y+=__shfl_xor(A.y,16); A.z+=__shfl_xor(A.z,16); A.w+=__shfl_xor(A.w,16); \
  A.x+=__shfl_xor(A.x,32); A.y+=__shfl_xor(A.y,32); A.z+=__shfl_xor(A.z,32); A.w+=__shfl_xor(A.w,32);
  MRG(a0) MRG(a1) MRG(a2) MRG(a3) MRG(a4) MRG(a5) MRG(a6) MRG(a7)
#undef MRG

  // ---- cross-wave merge via LDS -> block partial at index k ----
  __shared__ float msh[4], lsh[4];
  __shared__ float accsh[4][Cn];
  if (lane == 0) { msh[wave] = mw; lsh[wave] = lw; }
  if (slot == 0) {
    float4* arow = (float4*)accsh[wave];
    arow[l16 +  0] = a0;  arow[l16 + 16] = a1;
    arow[l16 + 32] = a2;  arow[l16 + 48] = a3;
    arow[l16 + 64] = a4;  arow[l16 + 80] = a5;
    arow[l16 + 96] = a6;  arow[l16 +112] = a7;
  }
  __syncthreads();

  const float Mb = fmaxf(fmaxf(msh[0], msh[1]), fmaxf(msh[2], msh[3]));
  const float e0 = __expf(msh[0] - Mb), e1 = __expf(msh[1] - Mb);
  const float e2 = __expf(msh[2] - Mb), e3 = __expf(msh[3] - Mb);
  float* pacc = ws + WS_PACC + (size_t)k * Cn;
  for (int ch = tid; ch < Cn; ch += 256)
    pacc[ch] = e0 * accsh[0][ch] + e1 * accsh[1][ch]
             + e2 * accsh[2][ch] + e3 * accsh[3][ch];
  if (tid == 0) {
    ws[WS_PM + k] = Mb;
    ws[WS_PL + k] = e0 * lsh[0] + e1 * lsh[1] + e2 * lsh[2] + e3 * lsh[3];
  }

  // ---- grid barrier: arrive; first NBLK-NFIN arrivers exit ----
  unsigned* bar = (unsigned*)ws + WS_BAR;
  __shared__ unsigned oldsh;
  __syncthreads();                       // pacc/PM/PL writes issued block-wide
  if (tid == 0) {
    __threadfence();                     // make partials visible device-wide
    oldsh = atomicAdd(bar, 1u);          // device-scope arrival
  }
  __syncthreads();
  const unsigned old = oldsh;
  if (old < NBLK - NFIN) return;

  // ---- finalize: last NFIN arrivers, unit chosen by arrival order ----
  const int unit = (NBLK - 1) - (int)old;              // 0..NFIN-1
  const int fb = unit >> 3, fp = unit & 7;
  if (tid == 0) {
    while (atomicAdd(bar, 0u) < NBLK)                  // coherent poll
      __builtin_amdgcn_s_sleep(8);
    __threadfence();
  }
  __syncthreads();

  int offb, cntb;                        // cntb <= 65 < 128
  ga_batch_range(lens, fb, offb, cntb);

  __shared__ float wgt[128];
  __shared__ float red[4][64];
  __shared__ float Msh, Lish;

  if (tid < 64) {
    const float m0 = (tid      < cntb) ? ws[WS_PM + offb + tid]      : NEG_BIG;
    const float m1 = (tid + 64 < cntb) ? ws[WS_PM + offb + tid + 64] : NEG_BIG;
    float mm = fmaxf(m0, m1);
#pragma unroll
    for (int off = 32; off; off >>= 1) mm = fmaxf(mm, __shfl_xor(mm, off));
    const float w0 = __expf(m0 - mm);                  // invalid -> 0
    const float w1 = __expf(m1 - mm);
    wgt[tid] = w0;  wgt[tid + 64] = w1;
    float li = 0.f;
    if (tid      < cntb) li += ws[WS_PL + offb + tid]      * w0;
    if (tid + 64 < cntb) li += ws[WS_PL + offb + tid + 64] * w1;
#pragma unroll
    for (int off = 32; off; off >>= 1) li += __shfl_xor(li, off);
    if (tid == 0) { Msh = mm; Lish = 1.f / li; }
  }
  __syncthreads();
  const float M = Msh, Li = Lish;

  // attn_h: channels [64*fp, 64*fp+64)
  {
    const int c = fp * 64 + (tid & 63), g = tid >> 6;
    const float* fpacc = ws + WS_PACC + (size_t)offb * Cn;
    float s = 0.f;
    for (int i = g; i < cntb; i += 4) s += wgt[i] * fpacc[(size_t)i * Cn + c];
    red[g][tid & 63] = s;
    __syncthreads();
    if (tid < 64)
      out[fb * Cn + fp * 64 + tid] =
          (red[0][tid] + red[1][tid] + red[2][tid] + red[3][tid]) * Li;
  }

  // align_vectors: s in [1024*fp, 1024*fp+1024)
  {
    const int flen = lens[fb];
    const float* al = ws + WS_ALIGN + (size_t)fb * Sn;
    float* ao = out + Bn * Cn + (size_t)fb * Sn;
    const int s0 = fp * 1024 + tid * 4;
    const float4 v = *(const float4*)(al + s0);  // s>=len lanes read stale ws,
    float4 o;                                    // discarded by the selects:
    o.x = (s0 + 0 < flen) ? __expf(v.x - M) * Li : 0.f;
    o.y = (s0 + 1 < flen) ? __expf(v.y - M) * Li : 0.f;
    o.z = (s0 + 2 < flen) ? __expf(v.z - M) * Li : 0.f;
    o.w = (s0 + 3 < flen) ? __expf(v.w - M) * Li : 0.f;
    *(float4*)(ao + s0) = o;
  }
}

// ---------------------------------------------------------------------------
extern "C" void kernel_launch(void* const* d_in, const int* in_sizes, int n_in,
                              void* d_out, int out_size, void* d_ws, size_t ws_size,
                              hipStream_t stream) {
  const float* input   = (const float*)d_in[0];
  const float* context = (const float*)d_in[1];
  const float* Wa      = (const float*)d_in[2];
  const float* Ua      = (const float*)d_in[3];
  const float* va      = (const float*)d_in[4];
  const int*   lens    = (const int*)d_in[5];
  float* out = (float*)d_out;
  float* ws  = (float*)d_ws;

  ga_prep<<<13, 256, 0, stream>>>(input, Wa, Ua, va, lens, ws);
  ga_fused<<<NBLK, 256, 0, stream>>>(context, lens, ws, out);
}

// Round 10
// 102.701 us; speedup vs baseline: 1.5676x; 1.5676x over previous
//
#include <hip/hip_runtime.h>
#include <math.h>

// Sizes fixed by the reference problem.
#define Bn 32
#define Sn 8192
#define Dn 256
#define Cn 512                 // 2*D
#define NBLK 1024              // ga_main grid = exactly 4 blocks/CU x 256 CUs
#define NEG_BIG (-1e30f)

// Workspace layout (float offsets). ~3.2 MiB total.
#define WS_U     0                          // [512]  u[c] = sum_d va[d]*Ua[d,c]
#define WS_QV    512                        // [32]   qv[b] = input[b] . (Wa^T va)
#define WS_PM    544                        // [NBLK] per-block running max
#define WS_PL    (WS_PM + NBLK)             // [NBLK] per-block exp-sum
#define WS_PLAN  (WS_PL + NBLK)             // [NBLK] packed (b,t0,t1) ints
#define WS_ALIGN (WS_PLAN + NBLK)           // [B*S] raw align (valid rows only)
#define WS_PACC  (WS_ALIGN + Bn * Sn)       // [NBLK*Cn] per-block weighted ctx

// ---------------------------------------------------------------------------
// Length-proportional partition of the global 16-row-tile space.
// NT_b = ceil(len_b/16); batch b owns block range [f(P_b), f(P_b+NT_b)),
// f(P) = P*NBLK/TOT (floor). Telescoping => ranges exactly tile [0,NBLK).
// Within a batch, block j of cnt covers tiles [j*NT/cnt,(j+1)*NT/cnt).
// cnt <= NT*NBLK/TOT + 1 <= 65 <= 128 (lens >= S/2 => TOT >= 8448), and
// cnt <= NT so every block gets >= 1 tile. All int32 safe.
__device__ inline void ga_partition(const int* __restrict__ lens, int k,
                                    int& b, int& t0, int& t1) {
  int TOT = 0;
#pragma unroll
  for (int i = 0; i < Bn; ++i) TOT += (lens[i] + 15) >> 4;
  int P = 0, bb = 0, offb = 0, cntb = 1, ntb = 1;
#pragma unroll
  for (int i = 0; i < Bn; ++i) {
    const int nt = (lens[i] + 15) >> 4;
    const int o0 = (P * NBLK) / TOT;
    const int o1 = ((P + nt) * NBLK) / TOT;
    if (k >= o0 && k < o1) { bb = i; offb = o0; cntb = o1 - o0; ntb = nt; }
    P += nt;
  }
  const int j = k - offb;
  b = bb;
  t0 = (j * ntb) / cntb;
  t1 = ((j + 1) * ntb) / cntb;
}

__device__ inline void ga_batch_range(const int* __restrict__ lens, int b,
                                      int& offb, int& cntb) {
  int TOT = 0;
#pragma unroll
  for (int i = 0; i < Bn; ++i) TOT += (lens[i] + 15) >> 4;
  int P = 0;
  for (int i = 0; i < b; ++i) P += (lens[i] + 15) >> 4;
  const int nt = (lens[b] + 15) >> 4;
  offb = (P * NBLK) / TOT;
  cntb = ((P + nt) * NBLK) / TOT - offb;
}

// ---------------------------------------------------------------------------
// K1: ONE dispatch does all prep, no cross-block dependencies (R9-verified).
//   blocks 0..7 : u[64bx..64bx+64) -- each block reduces its 4 row-quarters
//                 in LDS (direct column result, no global partials)
//   block  8    : w[d] = sum_e va[e]*Wa[e,d], then qv[b] = input[b].w
//   blocks 9..12: partition plan (one packed entry per ga_main block)
__global__ __launch_bounds__(256) void ga_prep(const float* __restrict__ input,
                                               const float* __restrict__ Wa,
                                               const float* __restrict__ Ua,
                                               const float* __restrict__ va,
                                               const int* __restrict__ lens,
                                               float* __restrict__ ws) {
  const int tid = threadIdx.x, bx = blockIdx.x;
  if (bx < 8) {
    const int c = bx * 64 + (tid & 63);
    const int q = tid >> 6;                 // row quarter
    float acc = 0.f;
#pragma unroll 8
    for (int i = 0; i < 64; ++i) {
      const int d = q * 64 + i;
      acc += va[d] * Ua[(size_t)d * Cn + c];
    }
    __shared__ float sh[4][64];
    sh[q][tid & 63] = acc;
    __syncthreads();
    if (tid < 64)
      ws[WS_U + bx * 64 + tid] = sh[0][tid] + sh[1][tid] + sh[2][tid] + sh[3][tid];
  } else if (bx == 8) {
    __shared__ float wsh[Dn];
    float acc = 0.f;
#pragma unroll 8
    for (int e = 0; e < Dn; ++e)
      acc += va[e] * Wa[(size_t)e * Dn + tid];   // coalesced across tid
    wsh[tid] = acc;
    __syncthreads();
    const int b = tid >> 3, l8 = tid & 7;   // 8 threads per batch
    float p = 0.f;
#pragma unroll
    for (int j = 0; j < Dn / 8; ++j) {
      const int d = l8 + j * 8;
      p += input[b * Dn + d] * wsh[d];
    }
    p += __shfl_xor(p, 1);
    p += __shfl_xor(p, 2);
    p += __shfl_xor(p, 4);
    if (l8 == 0) ws[WS_QV + b] = p;
  } else {
    const int k = (bx - 9) * 256 + tid;     // 0..NBLK-1
    int b, t0, t1;
    ga_partition(lens, k, b, t0, t1);
    ((int*)ws)[WS_PLAN + k] = b | (t0 << 5) | (t1 << 17);  // 5+12+12 bits
  }
}

// ---------------------------------------------------------------------------
// K2 (R8-verified structure): NBLK blocks, 4 waves each; per iteration a
// block processes one 16-row tile (wave w rows: t*16 + w*4 + slot). Each
// 16-lane group owns one row: lane l holds float4 chunks (l&15)+16j, j=0..7;
// row-dot reduce = 4 shfl_xor; each wave keeps FOUR independent online-
// softmax streams in lane groups. 8 KiB of loads in flight per wave, all 8
// loads immediate-offset off one vaddr. Masked rows: branch-free no-op.
__global__ __launch_bounds__(256, 4) void ga_main(const float* __restrict__ context,
                                                  const int* __restrict__ lens,
                                                  float* __restrict__ ws) {
  const int k = blockIdx.x;
  const int plan = ((const int*)ws)[WS_PLAN + k];
  const int b  = plan & 31;
  const int t0 = (plan >> 5)  & 0xFFF;
  const int t1 = (plan >> 17) & 0xFFF;
  const int tid  = threadIdx.x;
  const int wave = tid >> 6;
  const int lane = tid & 63;
  const int l16  = lane & 15;          // chunk id within row
  const int slot = lane >> 4;          // stream id within wave
  const int len = lens[b];
  const float qv = ws[WS_QV + b];

  // u fragment: fixed per lane, loaded once (32 VGPR)
  const float4* uv = (const float4*)(ws + WS_U);
  float4 u0 = uv[l16 +  0], u1 = uv[l16 + 16], u2 = uv[l16 + 32], u3 = uv[l16 + 48];
  float4 u4 = uv[l16 + 64], u5 = uv[l16 + 80], u6 = uv[l16 + 96], u7 = uv[l16 + 112];

  float m = NEG_BIG, l = 0.f;
  float4 a0 = make_float4(0.f,0.f,0.f,0.f), a1 = a0, a2 = a0, a3 = a0;
  float4 a4 = a0, a5 = a0, a6 = a0, a7 = a0;

  const float* cbase = context + (size_t)b * Sn * Cn;
  float* alout = ws + WS_ALIGN + (size_t)b * Sn;

  for (int t = t0; t < t1; ++t) {
    const int s = t * 16 + wave * 4 + slot;            // < Sn always
    const float4* p = (const float4*)(cbase + (size_t)s * Cn) + l16;
    const float4 f0 = p[0],  f1 = p[16], f2 = p[32], f3 = p[48];
    const float4 f4 = p[64], f5 = p[80], f6 = p[96], f7 = p[112];

    float dot = f0.x*u0.x + f0.y*u0.y + f0.z*u0.z + f0.w*u0.w
              + f1.x*u1.x + f1.y*u1.y + f1.z*u1.z + f1.w*u1.w
              + f2.x*u2.x + f2.y*u2.y + f2.z*u2.z + f2.w*u2.w
              + f3.x*u3.x + f3.y*u3.y + f3.z*u3.z + f3.w*u3.w
              + f4.x*u4.x + f4.y*u4.y + f4.z*u4.z + f4.w*u4.w
              + f5.x*u5.x + f5.y*u5.y + f5.z*u5.z + f5.w*u5.w
              + f6.x*u6.x + f6.y*u6.y + f6.z*u6.z + f6.w*u6.w
              + f7.x*u7.x + f7.y*u7.y + f7.z*u7.z + f7.w*u7.w;
    dot += __shfl_xor(dot, 1);
    dot += __shfl_xor(dot, 2);
    dot += __shfl_xor(dot, 4);
    dot += __shfl_xor(dot, 8);                         // full row dot in group

    const bool valid = (s < len);
    const float al = valid ? (qv + dot) : -INFINITY;
    if (l16 == 0 && valid) alout[s] = al;

    const float mn = fmaxf(m, al);                     // invalid: mn=m
    const float sc = __expf(m - mn);                   // invalid: exp(0)=1
    const float pw = __expf(al - mn);                  // invalid: exp(-inf)=0
    l = l * sc + pw;
    a0.x=a0.x*sc+pw*f0.x; a0.y=a0.y*sc+pw*f0.y; a0.z=a0.z*sc+pw*f0.z; a0.w=a0.w*sc+pw*f0.w;
    a1.x=a1.x*sc+pw*f1.x; a1.y=a1.y*sc+pw*f1.y; a1.z=a1.z*sc+pw*f1.z; a1.w=a1.w*sc+pw*f1.w;
    a2.x=a2.x*sc+pw*f2.x; a2.y=a2.y*sc+pw*f2.y; a2.z=a2.z*sc+pw*f2.z; a2.w=a2.w*sc+pw*f2.w;
    a3.x=a3.x*sc+pw*f3.x; a3.y=a3.y*sc+pw*f3.y; a3.z=a3.z*sc+pw*f3.z; a3.w=a3.w*sc+pw*f3.w;
    a4.x=a4.x*sc+pw*f4.x; a4.y=a4.y*sc+pw*f4.y; a4.z=a4.z*sc+pw*f4.z; a4.w=a4.w*sc+pw*f4.w;
    a5.x=a5.x*sc+pw*f5.x; a5.y=a5.y*sc+pw*f5.y; a5.z=a5.z*sc+pw*f5.z; a5.w=a5.w*sc+pw*f5.w;
    a6.x=a6.x*sc+pw*f6.x; a6.y=a6.y*sc+pw*f6.y; a6.z=a6.z*sc+pw*f6.z; a6.w=a6.w*sc+pw*f6.w;
    a7.x=a7.x*sc+pw*f7.x; a7.y=a7.y*sc+pw*f7.y; a7.z=a7.z*sc+pw*f7.z; a7.w=a7.w*sc+pw*f7.w;
    m = mn;
  }

  // ---- merge the wave's 4 lane-group streams (once per block) ----
  float mw = fmaxf(m, __shfl_xor(m, 16));
  mw = fmaxf(mw, __shfl_xor(mw, 32));
  const float fS = __expf(m - mw);                     // empty stream -> 0
  float lw = l * fS;
  lw += __shfl_xor(lw, 16);
  lw += __shfl_xor(lw, 32);
#define MRG(A) \
  A.x*=fS; A.y*=fS; A.z*=fS; A.w*=fS; \
  A.x+=__shfl_xor(A.x,16); A.y+=__shfl_xor(A.y,16); A.z+=__shfl_xor(A.z,16); A.w+=__shfl_xor(A.w,16); \
  A.x+=__shfl_xor(A.x,32); A.y+=__shfl_xor(A.y,32); A.z+=__shfl_xor(A.z,32); A.w+=__shfl_xor(A.w,32);
  MRG(a0) MRG(a1) MRG(a2) MRG(a3) MRG(a4) MRG(a5) MRG(a6) MRG(a7)
#undef MRG

  // ---- cross-wave merge via LDS -> block partial at index k ----
  __shared__ float msh[4], lsh[4];
  __shared__ float accsh[4][Cn];
  if (lane == 0) { msh[wave] = mw; lsh[wave] = lw; }
  if (slot == 0) {                                     // group 0 holds the sums
    float4* arow = (float4*)accsh[wave];
    arow[l16 +  0] = a0;  arow[l16 + 16] = a1;
    arow[l16 + 32] = a2;  arow[l16 + 48] = a3;
    arow[l16 + 64] = a4;  arow[l16 + 80] = a5;
    arow[l16 + 96] = a6;  arow[l16 +112] = a7;
  }
  __syncthreads();

  const float M = fmaxf(fmaxf(msh[0], msh[1]), fmaxf(msh[2], msh[3]));
  const float e0 = __expf(msh[0] - M), e1 = __expf(msh[1] - M);
  const float e2 = __expf(msh[2] - M), e3 = __expf(msh[3] - M);
  float* pacc = ws + WS_PACC + (size_t)k * Cn;
  for (int ch = tid; ch < Cn; ch += 256)
    pacc[ch] = e0 * accsh[0][ch] + e1 * accsh[1][ch]
             + e2 * accsh[2][ch] + e3 * accsh[3][ch];
  if (tid == 0) {
    ws[WS_PM + k] = M;
    ws[WS_PL + k] = e0 * lsh[0] + e1 * lsh[1] + e2 * lsh[2] + e3 * lsh[3];
  }
}

// ---------------------------------------------------------------------------
// K3 (R8-verified): 8 blocks per batch; cntb <= 65 handled 2-per-lane. Each
// block covers 64 channels of attn_h and 1024 positions of align_vectors.
__global__ __launch_bounds__(256) void ga_finalize(const float* __restrict__ ws,
                                                   const int* __restrict__ lens,
                                                   float* __restrict__ out) {
  const int b = blockIdx.x >> 3, p = blockIdx.x & 7;
  const int tid = threadIdx.x;
  int offb, cntb;
  ga_batch_range(lens, b, offb, cntb);

  __shared__ float wgt[128];
  __shared__ float red[4][64];
  __shared__ float Msh, Lish;

  if (tid < 64) {
    const float m0 = (tid      < cntb) ? ws[WS_PM + offb + tid]      : NEG_BIG;
    const float m1 = (tid + 64 < cntb) ? ws[WS_PM + offb + tid + 64] : NEG_BIG;
    float mm = fmaxf(m0, m1);
#pragma unroll
    for (int off = 32; off; off >>= 1) mm = fmaxf(mm, __shfl_xor(mm, off));
    const float w0 = __expf(m0 - mm);                  // invalid -> 0
    const float w1 = __expf(m1 - mm);
    wgt[tid] = w0;  wgt[tid + 64] = w1;
    float li = 0.f;
    if (tid      < cntb) li += ws[WS_PL + offb + tid]      * w0;
    if (tid + 64 < cntb) li += ws[WS_PL + offb + tid + 64] * w1;
#pragma unroll
    for (int off = 32; off; off >>= 1) li += __shfl_xor(li, off);
    if (tid == 0) { Msh = mm; Lish = 1.f / li; }
  }
  __syncthreads();
  const float M = Msh, Li = Lish;

  // attn_h: this block covers channels [64p, 64p+64)
  {
    const int c = p * 64 + (tid & 63), g = tid >> 6;
    const float* pacc = ws + WS_PACC + (size_t)offb * Cn;
    float s = 0.f;
    for (int i = g; i < cntb; i += 4) s += wgt[i] * pacc[(size_t)i * Cn + c];
    red[g][tid & 63] = s;
    __syncthreads();
    if (tid < 64)
      out[b * Cn + p * 64 + tid] =
          (red[0][tid] + red[1][tid] + red[2][tid] + red[3][tid]) * Li;
  }

  // align_vectors: this block covers s in [1024p, 1024p+1024)
  {
    const int len = lens[b];
    const float* al = ws + WS_ALIGN + (size_t)b * Sn;
    float* ao = out + Bn * Cn + (size_t)b * Sn;
    const int s0 = p * 1024 + tid * 4;
    const float4 v = *(const float4*)(al + s0);  // s>=len lanes read stale ws,
    float4 o;                                    // discarded by the selects:
    o.x = (s0 + 0 < len) ? __expf(v.x - M) * Li : 0.f;
    o.y = (s0 + 1 < len) ? __expf(v.y - M) * Li : 0.f;
    o.z = (s0 + 2 < len) ? __expf(v.z - M) * Li : 0.f;
    o.w = (s0 + 3 < len) ? __expf(v.w - M) * Li : 0.f;
    *(float4*)(ao + s0) = o;
  }
}

// ---------------------------------------------------------------------------
extern "C" void kernel_launch(void* const* d_in, const int* in_sizes, int n_in,
                              void* d_out, int out_size, void* d_ws, size_t ws_size,
                              hipStream_t stream) {
  const float* input   = (const float*)d_in[0];
  const float* context = (const float*)d_in[1];
  const float* Wa      = (const float*)d_in[2];
  const float* Ua      = (const float*)d_in[3];
  const float* va      = (const float*)d_in[4];
  const int*   lens    = (const int*)d_in[5];
  float* out = (float*)d_out;
  float* ws  = (float*)d_ws;

  ga_prep<<<13, 256, 0, stream>>>(input, Wa, Ua, va, lens, ws);
  ga_main<<<NBLK, 256, 0, stream>>>(context, lens, ws);
  ga_finalize<<<Bn * 8, 256, 0, stream>>>(ws, lens, out);
}